// Round 6
// baseline (282.769 us; speedup 1.0000x reference)
//
#include <hip/hip_runtime.h>

// SpaceGroupDenseLayer — real part: out[b,n,f] = sum_i xr*wr - xi*wi + br  (8.39M fp32)
// R6: three-phase, ws-staged, m97-style GEMM.
//   prep_x : A_ws[b][n][512] bf16 = [xr | -xi]           (concat-K, cvt fused)
//   prep_w : B_ws[b][f][512] bf16 = [wr[sg];wi[sg]]^T    (gather+transpose via LDS tile, once)
//   gemm   : all-bf16, k-contig operands -> global_load_lds(16B) staging, zero staging VALU.
//            XOR-swizzled LDS chunk placement (encoded in per-lane GLOBAL addresses; LDS side
//            is wave-uniform base + lane*16) -> unpadded ds_read_b128 frag reads conflict-free.
//            MFMA frag layouts identical to the R5-verified kernel.

#define BB 64
#define NN 256
#define KK 256
#define FF 512
#define KC 512         // concat K
#define NSG 230
#define BM 128
#define BF 128
#define BK 64

typedef __attribute__((ext_vector_type(8))) short bf16x8;
typedef __attribute__((ext_vector_type(4))) float f32x4;

#if __has_builtin(__builtin_amdgcn_cvt_pk_bf16_f32)
typedef __bf16 bf16x2_t __attribute__((ext_vector_type(2)));
__device__ __forceinline__ unsigned pack_bf16(float a, float b) {
    bf16x2_t r = __builtin_amdgcn_cvt_pk_bf16_f32(a, b);
    return __builtin_bit_cast(unsigned, r);
}
#else
__device__ __forceinline__ unsigned pack_bf16(float a, float b) {
    unsigned ua = __float_as_uint(a);
    unsigned ub = __float_as_uint(b);
    ua += 0x7fffu + ((ua >> 16) & 1u);   // RNE
    ub += 0x7fffu + ((ub >> 16) & 1u);
    return (ua >> 16) | (ub & 0xffff0000u);
}
#endif

__device__ __forceinline__ void gld_lds16(const void* g, void* l) {
    __builtin_amdgcn_global_load_lds(
        (const __attribute__((address_space(1))) unsigned int*)g,
        (__attribute__((address_space(3))) unsigned int*)l, 16, 0, 0);
}

__device__ __forceinline__ int clamp_sg(int s) {
    return (s < 0) ? 0 : ((s >= NSG) ? (NSG - 1) : s);
}

// ---- phase 1a: x -> bf16 concat-K (grid 4096 x 256) ----
__global__ __launch_bounds__(256) void prep_x(
    const float* __restrict__ xr, const float* __restrict__ xi,
    unsigned short* __restrict__ Aws)
{
    const int g   = blockIdx.x * 256 + threadIdx.x;
    const int row = g >> 6;        // b*NN + n
    const int ch  = g & 63;        // 8-elem chunk within concat-K
    const float* src;
    float s;
    if (ch < 32) { src = xr + (size_t)row * KK + ch * 8;        s =  1.f; }
    else         { src = xi + (size_t)row * KK + (ch - 32) * 8; s = -1.f; }
    const float4 v0 = ((const float4*)src)[0];
    const float4 v1 = ((const float4*)src)[1];
    uint4 o;
    o.x = pack_bf16(s * v0.x, s * v0.y);
    o.y = pack_bf16(s * v0.z, s * v0.w);
    o.z = pack_bf16(s * v1.x, s * v1.y);
    o.w = pack_bf16(s * v1.z, s * v1.w);
    *(uint4*)&Aws[(size_t)row * KC + ch * 8] = o;
}

// ---- phase 1b: gather + transpose + cvt W (grid 64*8*8 x 256) ----
__global__ __launch_bounds__(256) void prep_w(
    const int* __restrict__ sg_g,
    const float* __restrict__ wr, const float* __restrict__ wi,
    unsigned short* __restrict__ Bws)
{
    __shared__ float tile[64][65];   // +1 pad breaks transpose-read conflicts

    const int bx = blockIdx.x;
    const int b  = bx >> 6;
    const int kt = (bx >> 3) & 7;    // concat-k tile (64 wide)
    const int ft = bx & 7;           // f tile (64 wide)
    const int sg = clamp_sg(sg_g[b]);

    const int kc0 = kt * 64;
    const float* __restrict__ W = (kc0 < KK ? wr : wi)
        + (size_t)sg * KK * FF + (size_t)(kc0 & (KK - 1)) * FF + ft * 64;

    const int t    = threadIdx.x;
    const int krow = t >> 2;
    const int c4   = (t & 3) * 4;
    #pragma unroll
    for (int q = 0; q < 4; ++q) {
        const float4 v = *(const float4*)(W + (size_t)krow * FF + c4 + q * 16);
        tile[krow][c4 + q * 16 + 0] = v.x;
        tile[krow][c4 + q * 16 + 1] = v.y;
        tile[krow][c4 + q * 16 + 2] = v.z;
        tile[krow][c4 + q * 16 + 3] = v.w;
    }
    __syncthreads();

    const int frow = t >> 2;
    const int seg  = t & 3;          // 16 k-values per segment
    unsigned pk[8];
    #pragma unroll
    for (int j = 0; j < 8; ++j)
        pk[j] = pack_bf16(tile[seg * 16 + 2 * j][frow], tile[seg * 16 + 2 * j + 1][frow]);
    const size_t dst = ((size_t)(b * FF + ft * 64 + frow)) * KC + kc0 + seg * 16;
    *(uint4*)&Bws[dst]     = make_uint4(pk[0], pk[1], pk[2], pk[3]);
    *(uint4*)&Bws[dst + 8] = make_uint4(pk[4], pk[5], pk[6], pk[7]);
}

// ---- phase 2: bf16 MFMA GEMM, global_load_lds staging (grid 512 x 256) ----
__global__ __launch_bounds__(256, 2) void sg_gemm(
    const int* __restrict__ sg_g, const float* __restrict__ br_g,
    const unsigned short* __restrict__ Aws, const unsigned short* __restrict__ Bws,
    float* __restrict__ out, const int out_elems)
{
    __shared__ alignas(16) unsigned short As[BM * BK];  // 16 KB, no pad (gld_lds), XOR-swizzled
    __shared__ alignas(16) unsigned short Bs[BF * BK];  // 16 KB

    const int tid = threadIdx.x;
    const int bx  = blockIdx.x;
    const int b    = bx >> 3;
    const int mblk = bx & 1;
    const int fblk = (bx >> 1) & 3;
    const int n0 = mblk * BM;
    const int f0 = fblk * BF;

    const int lane = tid & 63;
    const int wv   = tid >> 6;
    const int wm   = (wv & 1) * 64;
    const int wf   = (wv >> 1) * 64;
    const int fr   = lane & 15;
    const int quad = lane >> 4;

    // staging geometry: per (issue q, wave) -> 8 rows; lane l -> row l>>3, chunk slot l&7.
    // LDS slot (l&7) holds global chunk ((l&7) ^ (l>>3))  [XOR swizzle].
    const int srow  = lane >> 3;                       // row within 8-row group
    const int schnk = ((lane & 7) ^ srow) * 8;         // swizzled k-offset (ushorts)

    f32x4 acc[4][4];
    #pragma unroll
    for (int i = 0; i < 4; ++i)
        #pragma unroll
        for (int j = 0; j < 4; ++j)
            acc[i][j] = (f32x4){0.f, 0.f, 0.f, 0.f};

    const unsigned short* Ab = Aws + (size_t)(b * NN + n0) * KC;
    const unsigned short* Bb = Bws + (size_t)(b * FF + f0) * KC;

    for (int s = 0; s < KC / BK; ++s) {
        const int k0 = s * BK;
        #pragma unroll
        for (int q = 0; q < 4; ++q) {
            const int m = (q * 4 + wv) * 8 + srow;
            gld_lds16(Ab + (size_t)m * KC + k0 + schnk, (void*)&As[(q * 4 + wv) * 512]);
        }
        #pragma unroll
        for (int q = 0; q < 4; ++q) {
            const int m = (q * 4 + wv) * 8 + srow;
            gld_lds16(Bb + (size_t)m * KC + k0 + schnk, (void*)&Bs[(q * 4 + wv) * 512]);
        }
        __syncthreads();

        #pragma unroll
        for (int kk = 0; kk < BK; kk += 32) {
            const int kb = kk >> 3;                    // 0 or 4
            bf16x8 af[4], bfr[4];
            #pragma unroll
            for (int i = 0; i < 4; ++i) {
                const int row = wm + i * 16 + fr;
                af[i] = *(const bf16x8*)&As[row * 64 + (((kb + quad) ^ (fr & 7)) * 8)];
            }
            #pragma unroll
            for (int j = 0; j < 4; ++j) {
                const int row = wf + j * 16 + fr;
                bfr[j] = *(const bf16x8*)&Bs[row * 64 + (((kb + quad) ^ (fr & 7)) * 8)];
            }
            #pragma unroll
            for (int i = 0; i < 4; ++i)
                #pragma unroll
                for (int j = 0; j < 4; ++j)
                    acc[i][j] = __builtin_amdgcn_mfma_f32_16x16x32_bf16(
                                    af[i], bfr[j], acc[i][j], 0, 0, 0);
        }
        __syncthreads();
    }

    const int sg = clamp_sg(sg_g[b]);
    #pragma unroll
    for (int j = 0; j < 4; ++j) {
        const int fcol = f0 + wf + j * 16 + fr;
        const float bias = br_g[sg * FF + fcol];
        #pragma unroll
        for (int i = 0; i < 4; ++i) {
            const int nb = n0 + wm + i * 16 + quad * 4;
            #pragma unroll
            for (int r = 0; r < 4; ++r) {
                const long long idx = (long long)(b * NN + nb + r) * FF + fcol;
                if (idx < out_elems) out[idx] = acc[i][j][r] + bias;
            }
        }
    }
}

extern "C" void kernel_launch(void* const* d_in, const int* in_sizes, int n_in,
                              void* d_out, int out_size, void* d_ws, size_t ws_size,
                              hipStream_t stream) {
    const float* xr = (const float*)d_in[0];
    const float* xi = (const float*)d_in[1];
    const int*   sg = (const int*)  d_in[2];
    const float* wr = (const float*)d_in[3];
    const float* wi = (const float*)d_in[4];
    const float* br = (const float*)d_in[5];
    float* out = (float*)d_out;

    unsigned short* Aws = (unsigned short*)d_ws;                       // 16.8 MB
    unsigned short* Bws = Aws + (size_t)BB * NN * KC;                  // 33.5 MB

    prep_x<<<dim3(4096), dim3(256), 0, stream>>>(xr, xi, Aws);
    prep_w<<<dim3(BB * 8 * 8), dim3(256), 0, stream>>>(sg, wr, wi, Bws);
    sg_gemm<<<dim3(BB * 2 * 4), dim3(256), 0, stream>>>(sg, br, Aws, Bws, out, out_size);
}